// Round 4
// baseline (242.277 us; speedup 1.0000x reference)
//
#include <hip/hip_runtime.h>
#include <stdint.h>

#define K_DIM 4096
#define N_DIM 11008
#define NCOL  1376   // N/8

typedef __attribute__((ext_vector_type(4))) float  f32x4;
typedef __attribute__((ext_vector_type(8))) __bf16 bf16x8;

__device__ __forceinline__ void gload_lds16(const void* g, void* l) {
  __builtin_amdgcn_global_load_lds((const __attribute__((address_space(1))) void*)g,
                                   (__attribute__((address_space(3))) void*)l,
                                   16, 0, 0);
}

// ---------- prologue 1: x fp32 -> bf16 ----------
__global__ void __launch_bounds__(256) convert_x_kernel(const float* __restrict__ x,
                                                        __bf16* __restrict__ a) {
  size_t i = ((size_t)blockIdx.x * 256u + threadIdx.x) * 8u;
  f32x4 v0 = *(const f32x4*)(x + i);
  f32x4 v1 = *(const f32x4*)(x + i + 4);
  bf16x8 o;
  o[0] = (__bf16)v0[0]; o[1] = (__bf16)v0[1]; o[2] = (__bf16)v0[2]; o[3] = (__bf16)v0[3];
  o[4] = (__bf16)v1[0]; o[5] = (__bf16)v1[1]; o[6] = (__bf16)v1[2]; o[7] = (__bf16)v1[3];
  *(bf16x8*)(a + i) = o;
}

// ---------- prologue 2: AWQ dequant -> Wt bf16 [N][K] (transposed via LDS) ----------
__global__ void __launch_bounds__(256) dequant_kernel(const int* __restrict__ qw,
                                                      const int* __restrict__ qz,
                                                      const float* __restrict__ sc,
                                                      __bf16* __restrict__ wt) {
  constexpr int SH[8] = {0, 16, 4, 20, 8, 24, 12, 28};  // AWQ [0,4,1,5,2,6,3,7]*4
  __shared__ __bf16 tile[64][72];
  const int bid = blockIdx.x;
  const int tk = bid & 63;
  const int tn = bid >> 6;
  const int k0 = tk * 64;
  const int c0 = tn * 8;
  const int t = threadIdx.x;
#pragma unroll
  for (int r = 0; r < 2; ++r) {
    int idx = r * 256 + t;
    int kk = idx >> 3;
    int cc = idx & 7;
    int k = k0 + kk;
    int c = c0 + cc;
    uint32_t q  = (uint32_t)qw[(size_t)k * NCOL + c];
    int g = k >> 7;
    uint32_t zq = (uint32_t)qz[(size_t)g * NCOL + c];
    const float* s = sc + (size_t)g * N_DIM + (size_t)c * 8;
#pragma unroll
    for (int j = 0; j < 8; ++j) {
      int wv = (int)((q >> SH[j]) & 15u) - (int)((zq >> SH[j]) & 15u);
      tile[cc * 8 + j][kk] = (__bf16)((float)wv * s[j]);
    }
  }
  __syncthreads();
  const int n0 = tn * 64;
#pragma unroll
  for (int r = 0; r < 2; ++r) {
    int idx = r * 256 + t;
    int row = idx >> 3;
    int kc = idx & 7;
    bf16x8 v = *(const bf16x8*)&tile[row][kc * 8];
    *(bf16x8*)(wt + (size_t)(n0 + row) * K_DIM + k0 + kc * 8) = v;
  }
}

// ---------- main GEMM: 256(M) x 128(N) tile, BK=64, simple 2-barrier loop ----------
// 4 waves (256 thr) as 2M x 2N, per-wave 128x64 = 8x4 frags of 16x16x32 bf16 MFMA.
// Fat waves: 0.75x ds_read traffic + addr work per FLOP vs 64x64 waves (R1).
// 48KB static LDS single buffer -> exactly 2 blocks/CU; each SIMD hosts 1 wave
// from each of 2 staggered blocks -> cross-block hiding of the barrier drain
// (m114 mechanism; this is what made R1 fast and R2/R3's 1-blk/CU slow).
// Granule-XOR swizzle: linear gload_lds dest + inverse-swizzled global source +
// swizzled ds_read (verified 0 bank conflicts R1-R3).
__global__ void __launch_bounds__(256, 2) wq_gemm_kernel(
    const __bf16* __restrict__ A,    // [M][K] bf16
    const __bf16* __restrict__ Wt,   // [N][K] bf16
    const float* __restrict__ bias,
    float* __restrict__ out,
    const int Mblk)
{
  __shared__ char As[32768];   // 256 rows x 64 bf16 (row stride 128B)
  __shared__ char Bs[16384];   // 128 rows x 64 bf16

  const int nwg = gridDim.x;
  int bid = blockIdx.x;
  if ((nwg & 7) == 0) {                 // XCD-aware swizzle (688 % 8 == 0, bijective)
    const int cpx = nwg >> 3;
    bid = (bid & 7) * cpx + (bid >> 3);
  }
  const int bm = bid % Mblk;            // m-fastest: XCD chunk reuses B panels in L2
  const int bn = bid / Mblk;
  const int m0 = bm * 256;
  const int n0 = bn * 128;

  const int t = threadIdx.x;
  const int lane = t & 63;
  const int w = t >> 6;      // 0..3
  const int wr = w >> 1;     // 0..1  (M half: 128 rows)
  const int wc = w & 1;      // 0..1  (N half: 64 cols)
  const int lrow = lane & 15;
  const int lk = lane >> 4;

  const __bf16* pA = A  + (size_t)m0 * K_DIM;
  const __bf16* pB = Wt + (size_t)n0 * K_DIM;

  // staging source offsets (elements): round i, cid = i*256+t
  uint32_t offA[8], offB[4];
#pragma unroll
  for (int i = 0; i < 8; ++i) {
    const int cid = i * 256 + t;
    const int rp = cid >> 3;
    const int gl = (cid & 7) ^ (rp & 7);
    offA[i] = (uint32_t)rp * K_DIM + (uint32_t)gl * 8;
  }
#pragma unroll
  for (int i = 0; i < 4; ++i) {
    const int cid = i * 256 + t;
    const int rp = cid >> 3;
    const int gl = (cid & 7) ^ (rp & 7);
    offB[i] = (uint32_t)rp * K_DIM + (uint32_t)gl * 8;
  }
  const int ldst = w * 1024;   // wave-linear LDS dest within each 4KB round

  f32x4 acc[8][4];
#pragma unroll
  for (int i = 0; i < 8; ++i)
#pragma unroll
    for (int j = 0; j < 4; ++j) acc[i][j] = (f32x4){0.f, 0.f, 0.f, 0.f};

  // compute-side LDS bases (row&7 == lrow&7 since 16|frag stride)
  const char* abase = As + (wr * 128 + lrow) * 128;
  const char* bbase = Bs + (wc * 64 + lrow) * 128;
  const int gk0 = (lk ^ (lrow & 7)) << 4;        // kk=0 granule byte offset
  const int gk1 = ((4 + lk) ^ (lrow & 7)) << 4;  // kk=1

  for (int kt = 0; kt < 64; ++kt) {
    const uint32_t koff = (uint32_t)kt * 64;
    __syncthreads();   // previous tile's compute done; LDS reusable
#pragma unroll
    for (int i = 0; i < 8; ++i)
      gload_lds16(pA + offA[i] + koff, As + i * 4096 + ldst);
#pragma unroll
    for (int i = 0; i < 4; ++i)
      gload_lds16(pB + offB[i] + koff, Bs + i * 4096 + ldst);
    __syncthreads();   // compiler drains vmcnt(0): staged tile visible

#pragma unroll
    for (int kk = 0; kk < 2; ++kk) {
      const int g = kk ? gk1 : gk0;
      bf16x8 av[8], bv[4];
#pragma unroll
      for (int m = 0; m < 8; ++m) av[m] = *(const bf16x8*)(abase + m * 2048 + g);
#pragma unroll
      for (int n = 0; n < 4; ++n) bv[n] = *(const bf16x8*)(bbase + n * 2048 + g);
#pragma unroll
      for (int m = 0; m < 8; ++m)
#pragma unroll
        for (int n = 0; n < 4; ++n)
          acc[m][n] = __builtin_amdgcn_mfma_f32_16x16x32_bf16(av[m], bv[n], acc[m][n], 0, 0, 0);
    }
  }

  // epilogue: C/D layout col=lane&15, row=(lane>>4)*4+reg (m89-verified, R1-R3-passed)
  const int orow = m0 + wr * 128 + lk * 4;
  const int ocol = n0 + wc * 64 + lrow;
#pragma unroll
  for (int n = 0; n < 4; ++n) {
    const int col = ocol + n * 16;
    const float bv = bias[col];
#pragma unroll
    for (int m = 0; m < 8; ++m) {
      float* po = out + (size_t)(orow + m * 16) * N_DIM + col;
      po[0]                 = acc[m][n][0] + bv;
      po[(size_t)N_DIM]     = acc[m][n][1] + bv;
      po[2 * (size_t)N_DIM] = acc[m][n][2] + bv;
      po[3 * (size_t)N_DIM] = acc[m][n][3] + bv;
    }
  }
}

extern "C" void kernel_launch(void* const* d_in, const int* in_sizes, int n_in,
                              void* d_out, int out_size, void* d_ws, size_t ws_size,
                              hipStream_t stream) {
  const float* x    = (const float*)d_in[0];
  const int* qw     = (const int*)d_in[1];
  const int* qz     = (const int*)d_in[2];
  const float* sc   = (const float*)d_in[3];
  const float* bias = (const float*)d_in[4];
  float* out = (float*)d_out;

  const int M = in_sizes[0] / K_DIM;        // 2048
  const int Mblk = M / 256;                 // 8
  const int grid = Mblk * (N_DIM / 128);    // 8 * 86 = 688 (divisible by 8)

  const size_t abytes = (size_t)M * K_DIM * 2;
  __bf16* Aw = (__bf16*)d_ws;
  __bf16* Wt = (__bf16*)((char*)d_ws + abytes);

  convert_x_kernel<<<(M * K_DIM) / 2048, 256, 0, stream>>>(x, Aw);
  dequant_kernel<<<(K_DIM / 64) * (N_DIM / 64), 256, 0, stream>>>(qw, qz, sc, Wt);

  wq_gemm_kernel<<<grid, 256, 0, stream>>>(Aw, Wt, bias, out, Mblk);
}